// Round 1
// baseline (198.028 us; speedup 1.0000x reference)
//
#include <hip/hip_runtime.h>

// SGE-style gate: B=64, C=512, HW=784, G=8, cpg=64.
// One block per (b,g) tile. Tile (64ch x 784pos = 196KB fp32) held in
// registers: 1024 threads x 49 floats. Single HBM read + single HBM write.
//
// Thread layout: t = c*16 + j  (c = channel 0..63, j = 0..15)
//   thread owns positions p = j + 16k, k = 0..48  (784 = 16*49)
//   -> each 16-thread group reads one aligned 64B run per k (fully coalesced
//      at cache-line granularity; channel stride 3136B = 49 lines).

#define HW   784
#define CPG  64
#define NG   8
#define KPT  49          // (CPG*HW)/1024 elements per thread

__global__ __launch_bounds__(1024, 8)
void sge_kernel(const float* __restrict__ x,
                const float* __restrict__ weight,
                const float* __restrict__ bias,
                float* __restrict__ out) {
    __shared__ float sbuf[16 * HW];   // wave-partials of s; row 0 reused for gate
    __shared__ float redbuf[32];      // block-reduce scratch (16 waves x {s, s^2})

    const int t    = threadIdx.x;
    const int c    = t >> 4;          // channel within group, 0..63
    const int j    = t & 15;          // sub-position, 0..15
    const int wave = t >> 6;          // 0..15
    const int lane = t & 63;

    const int bg = blockIdx.x;        // b*NG + g, 0..511 — group tile is contiguous
    const int g  = bg & (NG - 1);
    const size_t base = (size_t)bg * (CPG * HW);

    // ---- load tile slice into registers (one HBM read of x) ----
    const float* xp = x + base + (size_t)c * HW + j;
    float v[KPT];
#pragma unroll
    for (int k = 0; k < KPT; ++k) v[k] = xp[k * 16];

    // ---- per-channel spatial mean: 16 threads/channel, within one wave ----
    float cs = 0.f;
#pragma unroll
    for (int k = 0; k < KPT; ++k) cs += v[k];
    cs += __shfl_xor(cs, 1, 16);
    cs += __shfl_xor(cs, 2, 16);
    cs += __shfl_xor(cs, 4, 16);
    cs += __shfl_xor(cs, 8, 16);
    const float mean_c = cs * (1.0f / (float)HW);

    // ---- s[p] = sum_c v[c,p]*mean_c : intra-wave 4-channel partial ----
#pragma unroll
    for (int k = 0; k < KPT; ++k) {
        float w = v[k] * mean_c;
        w += __shfl_xor(w, 16, 64);   // sum the 4 channels resident in this wave
        w += __shfl_xor(w, 32, 64);
        if (lane < 16) sbuf[wave * HW + k * 16 + j] = w;  // p = j + 16k
    }
    __syncthreads();

    // ---- cross-wave sum: thread t (< 784) owns position p = t ----
    float s = 0.f;
    if (t < HW) {
#pragma unroll
        for (int w = 0; w < 16; ++w) s += sbuf[w * HW + t];
    }

    // ---- block reduction for mu, var over the 784 s values ----
    float rs = s, rs2 = s * s;
#pragma unroll
    for (int m = 1; m < 64; m <<= 1) {
        rs  += __shfl_xor(rs,  m, 64);
        rs2 += __shfl_xor(rs2, m, 64);
    }
    if (lane == 0) { redbuf[wave] = rs; redbuf[16 + wave] = rs2; }
    __syncthreads();

    float sum_s = 0.f, sum_s2 = 0.f;
#pragma unroll
    for (int w = 0; w < 16; ++w) { sum_s += redbuf[w]; sum_s2 += redbuf[16 + w]; }
    const float mu   = sum_s * (1.0f / (float)HW);
    const float var  = sum_s2 * (1.0f / (float)HW) - mu * mu;
    const float rstd = rsqrtf(var + 1e-5f);

    // ---- gate[p] = sigmoid(((s-mu)*rstd)*w_g + b_g), stored in sbuf row 0 ----
    const float wg = weight[g];
    const float bgv = bias[g];
    if (t < HW) {
        const float z = (s - mu) * rstd * wg + bgv;
        sbuf[t] = 1.0f / (1.0f + __expf(-z));
    }
    __syncthreads();

    // ---- epilogue: out = v * gate (gate read is an LDS broadcast) ----
    float* op = out + base + (size_t)c * HW + j;
#pragma unroll
    for (int k = 0; k < KPT; ++k) op[k * 16] = v[k] * sbuf[k * 16 + j];
}

extern "C" void kernel_launch(void* const* d_in, const int* in_sizes, int n_in,
                              void* d_out, int out_size, void* d_ws, size_t ws_size,
                              hipStream_t stream) {
    const float* x      = (const float*)d_in[0];
    const float* weight = (const float*)d_in[1];
    const float* bias   = (const float*)d_in[2];
    // d_in[3] = groups (int scalar) — fixed at 8, baked into the kernel.
    float* out = (float*)d_out;

    sge_kernel<<<dim3(512), dim3(1024), 0, stream>>>(x, weight, bias, out);
}